// Round 5
// baseline (128.586 us; speedup 1.0000x reference)
//
#include <hip/hip_runtime.h>

typedef __attribute__((ext_vector_type(8))) short bf16x8;
typedef __attribute__((ext_vector_type(4))) float f32x4;
typedef __attribute__((ext_vector_type(4))) int i32x4;
typedef __attribute__((ext_vector_type(4))) float float4v;

#define MFMA16(a, b, c) __builtin_amdgcn_mfma_f32_16x16x32_bf16((a), (b), (c), 0, 0, 0)

__device__ __forceinline__ unsigned short f2bf(float f) {
    unsigned u = __builtin_bit_cast(unsigned, f);
    u += 0x7fffu + ((u >> 16) & 1u);
    return (unsigned short)(u >> 16);
}
__device__ __forceinline__ float bf2f(unsigned short s) {
    unsigned u = ((unsigned)s) << 16;
    return __builtin_bit_cast(float, u);
}
__device__ __forceinline__ int pkbf(float a, float b) {
    return (int)f2bf(a) | ((int)f2bf(b) << 16);
}

// LDS map (bytes), total 149504 — see round-3 comments.
#define KOFF 131072
#define LOFF 147456

// ---------------------------------------------------------------------------
// Diagonal-block attention; runs AFTER the full D2D memcpy (out = x everywhere)
// and overwrites the diagonal blocks of `out` in place.
// ---------------------------------------------------------------------------
__global__ __launch_bounds__(512, 2) void battn_kernel(
    const float* __restrict__ x,
    const float* __restrict__ Wq, const float* __restrict__ bq,
    const float* __restrict__ Wk, const float* __restrict__ bk,
    const float* __restrict__ Wv, const float* __restrict__ bv,
    const float* __restrict__ gamma, float* __restrict__ out)
{
    __shared__ __attribute__((aligned(128))) char smem[149504];
    const int tid = threadIdx.x;
    const int p = blockIdx.x;
    const int ib = p >> 3, jb = p & 7;
    const int vbase = ib * 8 * 4096 + jb * 8 * 64 + ib * 8;
    const int lane = tid & 63, wv = tid >> 6;
    const int g = lane >> 4, c15 = lane & 15;

    // phase 0: stage x block -> blk^T bf16 (swizzled), batched 8-deep.
    #pragma unroll
    for (int b = 0; b < 4; ++b) {
        float4v t[8];
        #pragma unroll
        for (int j = 0; j < 8; ++j) {
            int ch = (b * 8 + j) * 512 + tid;
            int c = ch >> 7;
            int m = (ch & 127) * 4;
            int vox = ((m >> 6) << 12) + (((m >> 3) & 7) << 6) + (m & 7);
            t[j] = *(const float4v*)(x + c * 262144 + vbase + vox);
        }
        #pragma unroll
        for (int j = 0; j < 8; ++j) {
            int ch = (b * 8 + j) * 512 + tid;
            int c = ch >> 7;
            int m = (ch & 127) * 4;
            char* bp = smem + ((m * 256 + 2 * c) ^ (((m >> 2) & 7) << 4));
            *(unsigned short*)(bp)       = f2bf(t[j][0]);
            *(unsigned short*)(bp + 256) = f2bf(t[j][1]);
            *(unsigned short*)(bp + 512) = f2bf(t[j][2]);
            *(unsigned short*)(bp + 768) = f2bf(t[j][3]);
        }
    }

    // weight fragments (fp32 global -> bf16 regs), vectorized float4 loads
    bf16x8 wqf[4], wkf[4], wvf[4];
    #pragma unroll
    for (int ks = 0; ks < 4; ++ks) {
        const float4v* sq = (const float4v*)(Wq + c15 * 128 + ks * 32 + g * 8);
        const float4v* sk = (const float4v*)(Wk + c15 * 128 + ks * 32 + g * 8);
        const float4v* sv = (const float4v*)(Wv + (wv * 16 + c15) * 128 + ks * 32 + g * 8);
        float4v q0 = sq[0], q1 = sq[1];
        float4v k0 = sk[0], k1 = sk[1];
        float4v v0 = sv[0], v1 = sv[1];
        #pragma unroll
        for (int e = 0; e < 4; ++e) {
            wqf[ks][e] = (short)f2bf(q0[e]); wqf[ks][4 + e] = (short)f2bf(q1[e]);
            wkf[ks][e] = (short)f2bf(k0[e]); wkf[ks][4 + e] = (short)f2bf(k1[e]);
            wvf[ks][e] = (short)f2bf(v0[e]); wvf[ks][4 + e] = (short)f2bf(v1[e]);
        }
    }
    const float bqv = bq[c15], bkv = bk[c15];
    const f32x4 zacc = {0.f, 0.f, 0.f, 0.f};
    const bf16x8 zfrag = (bf16x8)(short)0;

    __syncthreads();   // B1: blkT staged

    // P1: qhat (wave-local)
    #pragma unroll
    for (int qi = 0; qi < 4; ++qi) {
        f32x4 acc = zacc;
        int mrow = wv * 64 + qi * 16 + c15;
        int sw = ((mrow >> 2) & 7) << 4;
        #pragma unroll
        for (int ks = 0; ks < 4; ++ks) {
            bf16x8 af = *(const bf16x8*)(smem + ((mrow * 256 + ks * 64 + g * 16) ^ sw));
            acc = MFMA16(af, wqf[ks], acc);
        }
        #pragma unroll
        for (int r = 0; r < 4; ++r) {
            int nql = qi * 16 + g * 4 + r;
            *(unsigned short*)(smem + KOFF + wv * 2048 + nql * 32 + 2 * c15) = f2bf(acc[r] + bqv);
        }
    }
    bf16x8 qf[4];
    #pragma unroll
    for (int t = 0; t < 4; ++t) {
        bf16x8 v = zfrag;
        if (g < 2) v = *(const bf16x8*)(smem + KOFF + wv * 2048 + (t * 16 + c15) * 32 + g * 16);
        qf[t] = v;
    }

    // P2: Khat[mk][d] for this wave's 64 keys
    #pragma unroll
    for (int qi = 0; qi < 4; ++qi) {
        f32x4 acc = zacc;
        int mrow = wv * 64 + qi * 16 + c15;
        int sw = ((mrow >> 2) & 7) << 4;
        #pragma unroll
        for (int ks = 0; ks < 4; ++ks) {
            bf16x8 af = *(const bf16x8*)(smem + ((mrow * 256 + ks * 64 + g * 16) ^ sw));
            acc = MFMA16(af, wkf[ks], acc);
        }
        #pragma unroll
        for (int r = 0; r < 4; ++r) {
            int mk = wv * 64 + qi * 16 + g * 4 + r;
            *(unsigned short*)(smem + KOFF + mk * 32 + 2 * c15) = f2bf(acc[r] + bkv);
        }
    }

    // P3: Vhat in 4 chunks, in-place over consumed blkT rows
    for (int ck = 0; ck < 4; ++ck) {
        f32x4 vacc[8];
        #pragma unroll
        for (int mt = 0; mt < 8; ++mt) {
            vacc[mt] = zacc;
            int mrow = ck * 128 + mt * 16 + c15;
            int sw = ((mrow >> 2) & 7) << 4;
            #pragma unroll
            for (int ks = 0; ks < 4; ++ks) {
                bf16x8 bf = *(const bf16x8*)(smem + ((mrow * 256 + ks * 64 + g * 16) ^ sw));
                vacc[mt] = MFMA16(wvf[ks], bf, vacc[mt]);
            }
        }
        __syncthreads();
        #pragma unroll
        for (int mt = 0; mt < 8; ++mt) {
            #pragma unroll
            for (int r = 0; r < 4; ++r) {
                int c_out = wv * 16 + g * 4 + r;
                int mkl = mt * 16 + c15;
                *(unsigned short*)(smem + ck * 32768 + c_out * 256 +
                                   ((2 * mkl) ^ ((c_out & 7) << 4))) = f2bf(vacc[mt][r]);
            }
        }
    }
    __syncthreads();   // B3: Vhat + Khat visible

    // P4: barrier-free key-tile loop
    f32x4 o[4][8];
    #pragma unroll
    for (int t = 0; t < 4; ++t)
        #pragma unroll
        for (int ci = 0; ci < 8; ++ci)
            o[t][ci] = zacc;
    float lsum[4] = {0.f, 0.f, 0.f, 0.f};

    for (int kt = 0; kt < 16; ++kt) {
        int mk0 = kt * 32;
        bf16x8 ka[2];
        #pragma unroll
        for (int ki = 0; ki < 2; ++ki) {
            bf16x8 v = zfrag;
            if (g < 2) v = *(const bf16x8*)(smem + KOFF + (mk0 + ki * 16 + c15) * 32 + g * 16);
            ka[ki] = v;
        }

        bf16x8 pa[4];
        #pragma unroll
        for (int t = 0; t < 4; ++t) {
            f32x4 s0 = MFMA16(ka[0], qf[t], zacc);
            f32x4 s1 = MFMA16(ka[1], qf[t], zacc);
            float e00 = __expf(s0[0]), e01 = __expf(s0[1]), e02 = __expf(s0[2]), e03 = __expf(s0[3]);
            float e10 = __expf(s1[0]), e11 = __expf(s1[1]), e12 = __expf(s1[2]), e13 = __expf(s1[3]);
            lsum[t] += (e00 + e01) + (e02 + e03) + ((e10 + e11) + (e12 + e13));
            int wA0 = pkbf(e00, e01), wB0 = pkbf(e02, e03);
            int wA1 = pkbf(e10, e11), wB1 = pkbf(e12, e13);
            int src1 = ((2 * g) & 3) * 16 + c15;
            int src2 = ((2 * g + 1) & 3) * 16 + c15;
            int sA0a = __shfl(wA0, src1, 64), sA1a = __shfl(wA1, src1, 64);
            int sB0a = __shfl(wB0, src1, 64), sB1a = __shfl(wB1, src1, 64);
            int sA0b = __shfl(wA0, src2, 64), sA1b = __shfl(wA1, src2, 64);
            int sB0b = __shfl(wB0, src2, 64), sB1b = __shfl(wB1, src2, 64);
            bool k1 = (g >= 2);
            i32x4 uu = { k1 ? sA1a : sA0a, k1 ? sB1a : sB0a,
                         k1 ? sA1b : sA0b, k1 ? sB1b : sB0b };
            pa[t] = __builtin_bit_cast(bf16x8, uu);
        }

        int ckbase = (mk0 >> 7) * 32768;
        int mklb = (2 * (mk0 & 127)) + 16 * g;
        #pragma unroll
        for (int ci = 0; ci < 8; ++ci) {
            int c = ci * 16 + c15;
            bf16x8 vb = *(const bf16x8*)(smem + ckbase + c * 256 + (mklb ^ ((c & 7) << 4)));
            #pragma unroll
            for (int t = 0; t < 4; ++t)
                o[t][ci] = MFMA16(pa[t], vb, o[t][ci]);
        }
    }

    // softmax denominators
    #pragma unroll
    for (int t = 0; t < 4; ++t) {
        float l = lsum[t];
        l += __shfl_xor(l, 16, 64);
        l += __shfl_xor(l, 32, 64);
        if (g == 0)
            *(float*)(smem + LOFF + (wv * 64 + t * 16 + c15) * 4) = l;
    }

    __syncthreads();   // B4: Vhat reads done

    #pragma unroll
    for (int t = 0; t < 4; ++t)
        #pragma unroll
        for (int ci = 0; ci < 8; ++ci)
            #pragma unroll
            for (int r = 0; r < 4; ++r) {
                int nq = wv * 64 + t * 16 + g * 4 + r;
                int c = ci * 16 + c15;
                *(unsigned short*)(smem + c * 1024 + ((2 * nq) ^ ((c & 7) << 4))) = f2bf(o[t][ci][r]);
            }
    __syncthreads();   // B5: O visible

    // epilogue: out = gamma*(O/l + bv) + x, written directly over the (stale)
    // diagonal that the preceding memcpy left; x re-read fp32 (L3-hot).
    float gma = gamma[0];
    float invl = 1.0f / *(const float*)(smem + LOFF + tid * 4);
    int vox = ((tid >> 6) << 12) + (((tid >> 3) & 7) << 6) + (tid & 7);
    int go = vbase + vox;
    for (int cb = 0; cb < 16; ++cb) {
        float xv[8];
        #pragma unroll
        for (int j = 0; j < 8; ++j)
            xv[j] = x[(cb * 8 + j) * 262144 + go];
        #pragma unroll
        for (int j = 0; j < 8; ++j) {
            int c = cb * 8 + j;
            float ov = bf2f(*(const unsigned short*)(smem + c * 1024 + ((2 * tid) ^ ((c & 7) << 4))));
            out[c * 262144 + go] = gma * (ov * invl + bv[c]) + xv[j];
        }
    }
}

extern "C" void kernel_launch(void* const* d_in, const int* in_sizes, int n_in,
                              void* d_out, int out_size, void* d_ws, size_t ws_size,
                              hipStream_t stream) {
    const float* x     = (const float*)d_in[0];
    const float* Wq    = (const float*)d_in[1];
    const float* bq    = (const float*)d_in[2];
    const float* Wk    = (const float*)d_in[3];
    const float* bk    = (const float*)d_in[4];
    const float* Wv    = (const float*)d_in[5];
    const float* bv    = (const float*)d_in[6];
    const float* gamma = (const float*)d_in[7];
    float* out = (float*)d_out;
    (void)in_sizes; (void)n_in; (void)out_size; (void)d_ws; (void)ws_size;

    // Known-good tuned copy: out = x for ALL elements (diagonal stale, fixed below).
    hipMemcpyAsync(out, x, (size_t)out_size * sizeof(float),
                   hipMemcpyDeviceToDevice, stream);
    // Overwrite diagonal blocks with attention output (stream-ordered after copy).
    battn_kernel<<<dim3(64), dim3(512), 0, stream>>>(x, Wq, bq, Wk, bk, Wv, bv, gamma, out);
}

// Round 6
// 101.137 us; speedup vs baseline: 1.2714x; 1.2714x over previous
//
#include <hip/hip_runtime.h>

typedef __attribute__((ext_vector_type(8))) short bf16x8;
typedef __attribute__((ext_vector_type(4))) float f32x4;
typedef __attribute__((ext_vector_type(4))) int i32x4;
typedef __attribute__((ext_vector_type(4))) float float4v;

#define MFMA16(a, b, c) __builtin_amdgcn_mfma_f32_16x16x32_bf16((a), (b), (c), 0, 0, 0)

__device__ __forceinline__ unsigned short f2bf(float f) {
    unsigned u = __builtin_bit_cast(unsigned, f);
    u += 0x7fffu + ((u >> 16) & 1u);
    return (unsigned short)(u >> 16);
}
__device__ __forceinline__ float bf2f(unsigned short s) {
    unsigned u = ((unsigned)s) << 16;
    return __builtin_bit_cast(float, u);
}
__device__ __forceinline__ int pkbf(float a, float b) {
    return (int)f2bf(a) | ((int)f2bf(b) << 16);
}

// LDS map (bytes), total 147968:
//   [0, 131072)       blk^T bf16 [m=512][c=128], byte = (m*256 + 2c) ^ (((m>>2)&7)<<4)
//                     then (chunk ck): Vhat bf16, byte = ck*32768 + c*256 + (2*(mk&127) ^ ((c&7)<<4))
//                     then (after P4): O bf16 [c=128][nql=128], byte = c*256 + (2*nql ^ ((c&7)<<4))
//   [131072, 147456)  per-wave qhat scratch (wv*2048), then Khat bf16 [mk=512][d=16]: mk*32 + 2d
//   [147456, 147968)  l[128] f32 softmax denominators (wg-local queries)
#define KOFF 131072
#define LOFF 147456

// ---------------------------------------------------------------------------
// Diagonal-block attention, 4 workgroups per block p (256 wgs total).
// Workgroup (p, qq) owns queries [qq*128, qq*128+128); K/V computed locally.
// blockIdx mapping co-locates the 4 wgs of each p on one XCD (bid&7 = XCD
// under round-robin dispatch) so the 4x block re-read hits that XCD's L2.
// Runs AFTER the full D2D memcpy; overwrites diagonal of `out` in place.
// ---------------------------------------------------------------------------
__global__ __launch_bounds__(512, 2) void battn_kernel(
    const float* __restrict__ x,
    const float* __restrict__ Wq, const float* __restrict__ bq,
    const float* __restrict__ Wk, const float* __restrict__ bk,
    const float* __restrict__ Wv, const float* __restrict__ bv,
    const float* __restrict__ gamma, float* __restrict__ out)
{
    __shared__ __attribute__((aligned(128))) char smem[147968];
    const int tid = threadIdx.x;
    const int bid = blockIdx.x;
    const int p  = ((bid & 7) << 3) | (bid >> 5);   // 64 blocks
    const int qq = (bid >> 3) & 3;                  // query quarter
    const int ib = p >> 3, jb = p & 7;
    const int vbase = ib * 8 * 4096 + jb * 8 * 64 + ib * 8;
    const int lane = tid & 63, wv = tid >> 6;
    const int g = lane >> 4, c15 = lane & 15;

    // phase 0: stage FULL x block -> blk^T bf16 (swizzled), batched 8-deep.
    #pragma unroll
    for (int b = 0; b < 4; ++b) {
        float4v t[8];
        #pragma unroll
        for (int j = 0; j < 8; ++j) {
            int ch = (b * 8 + j) * 512 + tid;
            int c = ch >> 7;
            int m = (ch & 127) * 4;
            int vox = ((m >> 6) << 12) + (((m >> 3) & 7) << 6) + (m & 7);
            t[j] = *(const float4v*)(x + c * 262144 + vbase + vox);
        }
        #pragma unroll
        for (int j = 0; j < 8; ++j) {
            int ch = (b * 8 + j) * 512 + tid;
            int c = ch >> 7;
            int m = (ch & 127) * 4;
            char* bp = smem + ((m * 256 + 2 * c) ^ (((m >> 2) & 7) << 4));
            *(unsigned short*)(bp)       = f2bf(t[j][0]);
            *(unsigned short*)(bp + 256) = f2bf(t[j][1]);
            *(unsigned short*)(bp + 512) = f2bf(t[j][2]);
            *(unsigned short*)(bp + 768) = f2bf(t[j][3]);
        }
    }

    // weight fragments (fp32 global -> bf16 regs), vectorized float4 loads
    bf16x8 wqf[4], wkf[4], wvf[4];
    #pragma unroll
    for (int ks = 0; ks < 4; ++ks) {
        const float4v* sq = (const float4v*)(Wq + c15 * 128 + ks * 32 + g * 8);
        const float4v* sk = (const float4v*)(Wk + c15 * 128 + ks * 32 + g * 8);
        const float4v* sv = (const float4v*)(Wv + (wv * 16 + c15) * 128 + ks * 32 + g * 8);
        float4v q0 = sq[0], q1 = sq[1];
        float4v k0 = sk[0], k1 = sk[1];
        float4v v0 = sv[0], v1 = sv[1];
        #pragma unroll
        for (int e = 0; e < 4; ++e) {
            wqf[ks][e] = (short)f2bf(q0[e]); wqf[ks][4 + e] = (short)f2bf(q1[e]);
            wkf[ks][e] = (short)f2bf(k0[e]); wkf[ks][4 + e] = (short)f2bf(k1[e]);
            wvf[ks][e] = (short)f2bf(v0[e]); wvf[ks][4 + e] = (short)f2bf(v1[e]);
        }
    }
    const float bqv = bq[c15], bkv = bk[c15];
    const f32x4 zacc = {0.f, 0.f, 0.f, 0.f};
    const bf16x8 zfrag = (bf16x8)(short)0;

    __syncthreads();   // B1: blkT staged

    // P1: qhat for this wave's 16 queries (tile qq*128 + wv*16), wave-local
    {
        f32x4 acc = zacc;
        int mrow = qq * 128 + wv * 16 + c15;
        int sw = ((mrow >> 2) & 7) << 4;
        #pragma unroll
        for (int ks = 0; ks < 4; ++ks) {
            bf16x8 af = *(const bf16x8*)(smem + ((mrow * 256 + ks * 64 + g * 16) ^ sw));
            acc = MFMA16(af, wqf[ks], acc);
        }
        #pragma unroll
        for (int r = 0; r < 4; ++r)
            *(unsigned short*)(smem + KOFF + wv * 2048 + (g * 4 + r) * 32 + 2 * c15) = f2bf(acc[r] + bqv);
    }
    bf16x8 qf = zfrag;
    if (g < 2) qf = *(const bf16x8*)(smem + KOFF + wv * 2048 + c15 * 32 + g * 16);

    // P2: Khat[mk][d] for this wave's 64 keys (overwrites own scratch slice)
    #pragma unroll
    for (int qi = 0; qi < 4; ++qi) {
        f32x4 acc = zacc;
        int mrow = wv * 64 + qi * 16 + c15;
        int sw = ((mrow >> 2) & 7) << 4;
        #pragma unroll
        for (int ks = 0; ks < 4; ++ks) {
            bf16x8 af = *(const bf16x8*)(smem + ((mrow * 256 + ks * 64 + g * 16) ^ sw));
            acc = MFMA16(af, wkf[ks], acc);
        }
        #pragma unroll
        for (int r = 0; r < 4; ++r) {
            int mk = wv * 64 + qi * 16 + g * 4 + r;
            *(unsigned short*)(smem + KOFF + mk * 32 + 2 * c15) = f2bf(acc[r] + bkv);
        }
    }

    // P3: Vhat in 4 chunks of 128 keys, in-place over consumed blkT rows
    for (int ck = 0; ck < 4; ++ck) {
        f32x4 vacc[8];
        #pragma unroll
        for (int mt = 0; mt < 8; ++mt) {
            vacc[mt] = zacc;
            int mrow = ck * 128 + mt * 16 + c15;
            int sw = ((mrow >> 2) & 7) << 4;
            #pragma unroll
            for (int ks = 0; ks < 4; ++ks) {
                bf16x8 bf = *(const bf16x8*)(smem + ((mrow * 256 + ks * 64 + g * 16) ^ sw));
                vacc[mt] = MFMA16(wvf[ks], bf, vacc[mt]);
            }
        }
        __syncthreads();
        #pragma unroll
        for (int mt = 0; mt < 8; ++mt) {
            #pragma unroll
            for (int r = 0; r < 4; ++r) {
                int c_out = wv * 16 + g * 4 + r;
                int mkl = mt * 16 + c15;
                *(unsigned short*)(smem + ck * 32768 + c_out * 256 +
                                   ((2 * mkl) ^ ((c_out & 7) << 4))) = f2bf(vacc[mt][r]);
            }
        }
    }
    __syncthreads();   // B3: Vhat + Khat visible

    // P4: barrier-free key-tile loop. O[16q][128c] per wave, in regs.
    f32x4 o[8];
    #pragma unroll
    for (int ci = 0; ci < 8; ++ci) o[ci] = zacc;
    float lsum = 0.f;

    for (int kt = 0; kt < 16; ++kt) {
        int mk0 = kt * 32;
        bf16x8 ka[2];
        #pragma unroll
        for (int ki = 0; ki < 2; ++ki) {
            bf16x8 v = zfrag;
            if (g < 2) v = *(const bf16x8*)(smem + KOFF + (mk0 + ki * 16 + c15) * 32 + g * 16);
            ka[ki] = v;
        }

        f32x4 s0 = MFMA16(ka[0], qf, zacc);
        f32x4 s1 = MFMA16(ka[1], qf, zacc);
        float e00 = __expf(s0[0]), e01 = __expf(s0[1]), e02 = __expf(s0[2]), e03 = __expf(s0[3]);
        float e10 = __expf(s1[0]), e11 = __expf(s1[1]), e12 = __expf(s1[2]), e13 = __expf(s1[3]);
        lsum += (e00 + e01) + (e02 + e03) + ((e10 + e11) + (e12 + e13));
        int wA0 = pkbf(e00, e01), wB0 = pkbf(e02, e03);
        int wA1 = pkbf(e10, e11), wB1 = pkbf(e12, e13);
        int src1 = ((2 * g) & 3) * 16 + c15;
        int src2 = ((2 * g + 1) & 3) * 16 + c15;
        int sA0a = __shfl(wA0, src1, 64), sA1a = __shfl(wA1, src1, 64);
        int sB0a = __shfl(wB0, src1, 64), sB1a = __shfl(wB1, src1, 64);
        int sA0b = __shfl(wA0, src2, 64), sA1b = __shfl(wA1, src2, 64);
        int sB0b = __shfl(wB0, src2, 64), sB1b = __shfl(wB1, src2, 64);
        bool k1 = (g >= 2);
        i32x4 uu = { k1 ? sA1a : sA0a, k1 ? sB1a : sB0a,
                     k1 ? sA1b : sA0b, k1 ? sB1b : sB0b };
        bf16x8 pa = __builtin_bit_cast(bf16x8, uu);

        int ckbase = (mk0 >> 7) * 32768;
        int mklb = (2 * (mk0 & 127)) + 16 * g;
        #pragma unroll
        for (int ci = 0; ci < 8; ++ci) {
            int c = ci * 16 + c15;
            bf16x8 vb = *(const bf16x8*)(smem + ckbase + c * 256 + (mklb ^ ((c & 7) << 4)));
            o[ci] = MFMA16(pa, vb, o[ci]);
        }
    }

    // softmax denominators for this wave's 16 queries
    {
        float l = lsum;
        l += __shfl_xor(l, 16, 64);
        l += __shfl_xor(l, 32, 64);
        if (g == 0)
            *(float*)(smem + LOFF + (wv * 16 + c15) * 4) = l;
    }

    __syncthreads();   // B4: Vhat/Khat reads done, safe to overwrite with O

    #pragma unroll
    for (int ci = 0; ci < 8; ++ci)
        #pragma unroll
        for (int r = 0; r < 4; ++r) {
            int nql = wv * 16 + g * 4 + r;           // 0..127
            int c = ci * 16 + c15;
            *(unsigned short*)(smem + c * 256 + ((2 * nql) ^ ((c & 7) << 4))) = f2bf(o[ci][r]);
        }
    __syncthreads();   // B5: O visible

    // epilogue: out = gamma*(O/l + bv) + x over this wg's 128 queries.
    float gma = gamma[0];
    int q128 = tid & 127;                            // wg-local query
    int cb = tid >> 7;                               // channel block 0..3 (32 ch each)
    float invl = 1.0f / *(const float*)(smem + LOFF + q128 * 4);
    int nq = qq * 128 + q128;
    int vox = ((nq >> 6) << 12) + (((nq >> 3) & 7) << 6) + (nq & 7);
    int go = vbase + vox;
    #pragma unroll
    for (int b = 0; b < 4; ++b) {
        float xv[8];
        #pragma unroll
        for (int j = 0; j < 8; ++j) {
            int c = cb * 32 + b * 8 + j;
            xv[j] = x[c * 262144 + go];
        }
        #pragma unroll
        for (int j = 0; j < 8; ++j) {
            int c = cb * 32 + b * 8 + j;
            float ov = bf2f(*(const unsigned short*)(smem + c * 256 + ((2 * q128) ^ ((c & 7) << 4))));
            out[c * 262144 + go] = gma * (ov * invl + bv[c]) + xv[j];
        }
    }
}

extern "C" void kernel_launch(void* const* d_in, const int* in_sizes, int n_in,
                              void* d_out, int out_size, void* d_ws, size_t ws_size,
                              hipStream_t stream) {
    const float* x     = (const float*)d_in[0];
    const float* Wq    = (const float*)d_in[1];
    const float* bq    = (const float*)d_in[2];
    const float* Wk    = (const float*)d_in[3];
    const float* bk    = (const float*)d_in[4];
    const float* Wv    = (const float*)d_in[5];
    const float* bv    = (const float*)d_in[6];
    const float* gamma = (const float*)d_in[7];
    float* out = (float*)d_out;
    (void)in_sizes; (void)n_in; (void)out_size; (void)d_ws; (void)ws_size;

    // Known-good tuned copy: out = x for ALL elements (diagonal stale, fixed below).
    hipMemcpyAsync(out, x, (size_t)out_size * sizeof(float),
                   hipMemcpyDeviceToDevice, stream);
    // Overwrite diagonal blocks with attention output (stream-ordered after copy).
    battn_kernel<<<dim3(256), dim3(512), 0, stream>>>(x, Wq, bq, Wk, bk, Wv, bv, gamma, out);
}